// Round 9
// baseline (757.707 us; speedup 1.0000x reference)
//
#include <hip/hip_runtime.h>
#include <hip/hip_bf16.h>

#define BB 4
#define TT 2048
#define SSZ 2048
#define DQq 512
#define NH 8
#define HDim 64

typedef __attribute__((ext_vector_type(8))) short short8;
typedef __attribute__((ext_vector_type(4))) float f32x4;

__device__ __forceinline__ short f2bf(float f) {
    union { float f; unsigned u; } v; v.f = f;
    unsigned r = v.u + 0x7fffu + ((v.u >> 16) & 1u);
    return (short)(r >> 16);
}

// ---------------- weight transpose + bf16 convert: W[Kd][512] -> Wt[512][Kd]
// (verified round 5)
__global__ void wt_kernel(const float* __restrict__ W, short* __restrict__ Wt, int Kd) {
    int tid = blockIdx.x * 256 + threadIdx.x;
    int n = tid / Kd, k = tid - n * Kd;
    Wt[tid] = f2bf(W[(size_t)k * DQq + n]);
}

// ---------------- projection GEMM (verified round 5, unchanged)
template<int MODE, bool IN_BF16>
__global__ __launch_bounds__(256) void gemm_proj(
    const void* __restrict__ Xv, const short* __restrict__ Wt,
    const float* __restrict__ bias, void* __restrict__ Out, int Kd)
{
    __shared__ short As[64 * 40];
    __shared__ short Bs[64 * 40];
    int tid = threadIdx.x;
    int wave = tid >> 6, lane = tid & 63;
    int g = lane >> 4, r = lane & 15;
    int wm = wave >> 1, wn = wave & 1;
    int m0 = blockIdx.x * 64, n0 = blockIdx.y * 64;

    const float* Xf = (const float*)Xv;
    const short* Xb = (const short*)Xv;

    f32x4 acc[2][2];
    for (int a = 0; a < 2; ++a) for (int b2 = 0; b2 < 2; ++b2) acc[a][b2] = (f32x4){0.f,0.f,0.f,0.f};

    int lrow = tid >> 2, lk = (tid & 3) * 8;

    for (int k0 = 0; k0 < Kd; k0 += 32) {
        short8 av;
        if (IN_BF16) {
            av = *(const short8*)(Xb + (size_t)(m0 + lrow) * Kd + k0 + lk);
        } else {
            const f32x4* p = (const f32x4*)(Xf + (size_t)(m0 + lrow) * Kd + k0 + lk);
            f32x4 x0 = p[0], x1 = p[1];
            av[0]=f2bf(x0[0]); av[1]=f2bf(x0[1]); av[2]=f2bf(x0[2]); av[3]=f2bf(x0[3]);
            av[4]=f2bf(x1[0]); av[5]=f2bf(x1[1]); av[6]=f2bf(x1[2]); av[7]=f2bf(x1[3]);
        }
        *(short8*)(As + lrow * 40 + lk) = av;
        short8 bv = *(const short8*)(Wt + (size_t)(n0 + lrow) * Kd + k0 + lk);
        *(short8*)(Bs + lrow * 40 + lk) = bv;
        __syncthreads();
        short8 af[2], bf[2];
        for (int mi = 0; mi < 2; ++mi)
            af[mi] = *(short8*)(As + (wm*32 + mi*16 + r) * 40 + g*8);
        for (int ni = 0; ni < 2; ++ni)
            bf[ni] = *(short8*)(Bs + (wn*32 + ni*16 + r) * 40 + g*8);
        for (int mi = 0; mi < 2; ++mi)
            for (int ni = 0; ni < 2; ++ni)
                acc[mi][ni] = __builtin_amdgcn_mfma_f32_16x16x32_bf16(af[mi], bf[ni], acc[mi][ni], 0, 0, 0);
        __syncthreads();
    }

    for (int mi = 0; mi < 2; ++mi)
      for (int ni = 0; ni < 2; ++ni)
        for (int i = 0; i < 4; ++i) {
            int m = m0 + wm*32 + mi*16 + g*4 + i;
            int n = n0 + wn*32 + ni*16 + r;
            float v = acc[mi][ni][i] + bias[n];
            if (MODE == 0) {
                int b = m >> 11, t = m & 2047, h = n >> 6, hd = n & 63;
                ((short*)Out)[((((size_t)b*NH + h)*TT + t) << 6) + hd] = f2bf(v);
            } else if (MODE == 1) {
                int b = m >> 11, t = m & 2047, h = n >> 6, hd = n & 63;
                ((short*)Out)[(((size_t)b*NH + h)*HDim + hd)*SSZ + t] = f2bf(v);
            } else {
                ((float*)Out)[(size_t)m * DQq + n] = v;
            }
        }
}

// ---------------- attention weights only (verified round 8, unchanged)
__global__ __launch_bounds__(256) void attn_w(
    const short* __restrict__ Q, const short* __restrict__ K,
    const int* __restrict__ kpm, const float* __restrict__ amask,
    float* __restrict__ attnW)
{
    __shared__ float s_wm[4][16];
    __shared__ float s_wl[4][16];
    __shared__ float s_m[16];
    __shared__ float s_li[16];

    int tid = threadIdx.x;
    int wave = tid >> 6, lane = tid & 63;
    int g = lane >> 4, r = lane & 15;
    int t0 = blockIdx.x * 16;
    int bh = blockIdx.y;
    int b = bh >> 3;

    const short* Qp = Q + ((size_t)bh * TT + t0) * HDim;
    const short* Kp = K + (size_t)bh * SSZ * HDim;

    short8 qf0 = *(const short8*)(Qp + r * HDim + g * 8);
    short8 qf1 = *(const short8*)(Qp + r * HDim + 32 + g * 8);

    int ws0 = wave * 512;
    float mrun[4], lrun[4];
    for (int i = 0; i < 4; ++i) { mrun[i] = -1e30f; lrun[i] = 0.f; }

    // ---- phase 1: online stats (verified)
    for (int c = 0; c < 32; ++c) {
        int s_idx = ws0 + c * 16 + r;
        short8 kf0 = *(const short8*)(Kp + (size_t)s_idx * HDim + g * 8);
        short8 kf1 = *(const short8*)(Kp + (size_t)s_idx * HDim + 32 + g * 8);
        f32x4 sc = (f32x4){0.f,0.f,0.f,0.f};
        sc = __builtin_amdgcn_mfma_f32_16x16x32_bf16(qf0, kf0, sc, 0, 0, 0);
        sc = __builtin_amdgcn_mfma_f32_16x16x32_bf16(qf1, kf1, sc, 0, 0, 0);
        int ok = kpm[b * SSZ + s_idx];
        for (int i = 0; i < 4; ++i) {
            float v = sc[i] * 0.125f + amask[(size_t)(t0 + g*4 + i) * SSZ + s_idx];
            if (!ok) v = -1e30f;
            float mn = fmaxf(mrun[i], v);
            lrun[i] = lrun[i] * __expf(mrun[i] - mn) + __expf(v - mn);
            mrun[i] = mn;
        }
    }
    for (int i = 0; i < 4; ++i) {
        for (int off = 1; off < 16; off <<= 1) {
            float mo = __shfl_xor(mrun[i], off);
            float lo = __shfl_xor(lrun[i], off);
            float mn = fmaxf(mrun[i], mo);
            lrun[i] = lrun[i] * __expf(mrun[i] - mn) + lo * __expf(mo - mn);
            mrun[i] = mn;
        }
    }
    if (r == 0)
        for (int i = 0; i < 4; ++i) {
            s_wm[wave][g * 4 + i] = mrun[i];
            s_wl[wave][g * 4 + i] = lrun[i];
        }
    __syncthreads();
    if (tid < 16) {
        float m = -1e30f;
        for (int w = 0; w < 4; ++w) m = fmaxf(m, s_wm[w][tid]);
        float l = 0.f;
        for (int w = 0; w < 4; ++w) l += s_wl[w][tid] * __expf(s_wm[w][tid] - m);
        s_m[tid] = m;
        s_li[tid] = 1.0f / l;
    }
    __syncthreads();

    // ---- phase 2: recompute, normalize, write weights (verified pattern)
    float mr[4], lr[4];
    for (int i = 0; i < 4; ++i) { mr[i] = s_m[g*4 + i]; lr[i] = s_li[g*4 + i]; }

    for (int c2 = 0; c2 < 32; ++c2) {
        int s_idx = ws0 + c2 * 16 + r;
        short8 kf0 = *(const short8*)(Kp + (size_t)s_idx * HDim + g * 8);
        short8 kf1 = *(const short8*)(Kp + (size_t)s_idx * HDim + 32 + g * 8);
        f32x4 sc = (f32x4){0.f,0.f,0.f,0.f};
        sc = __builtin_amdgcn_mfma_f32_16x16x32_bf16(qf0, kf0, sc, 0, 0, 0);
        sc = __builtin_amdgcn_mfma_f32_16x16x32_bf16(qf1, kf1, sc, 0, 0, 0);
        int ok = kpm[b * SSZ + s_idx];
        for (int i = 0; i < 4; ++i) {
            float v = sc[i] * 0.125f + amask[(size_t)(t0 + g*4 + i) * SSZ + s_idx];
            if (!ok) v = -1e30f;
            float w = __expf(v - mr[i]) * lr[i];
            attnW[((size_t)bh * TT + t0 + g*4 + i) * SSZ + s_idx] = w;
        }
    }
}

// ---------------- PV via MFMA (verified round 8 indexing; CHANGED: unroll x4
// with batched loads for memory-level parallelism — was 28 VGPR, zero MLP,
// 0.93 TB/s latency-bound. Accumulation order unchanged -> identical numerics)
__global__ __launch_bounds__(256) void pv_mfma(
    const float* __restrict__ attnW, const short* __restrict__ Vt,
    float* __restrict__ AO)
{
    int tid = threadIdx.x;
    int wave = tid >> 6, lane = tid & 63;
    int g = lane >> 4, r = lane & 15;
    int t0 = blockIdx.x * 16;
    int bh = blockIdx.y;
    int b = bh >> 3, h = bh & 7;

    const float* wrow = attnW + ((size_t)bh * TT + t0 + r) * SSZ;
    const short* vrow = Vt + ((size_t)bh * HDim + wave * 16 + r) * SSZ;

    f32x4 oacc = (f32x4){0.f, 0.f, 0.f, 0.f};
    for (int c = 0; c < 64; c += 4) {
        f32x4 w0[4], w1[4];
        short8 vf[4];
        #pragma unroll
        for (int u = 0; u < 4; ++u) {
            int col0 = (c + u) * 32 + g * 8;
            w0[u] = *(const f32x4*)(wrow + col0);
            w1[u] = *(const f32x4*)(wrow + col0 + 4);
            vf[u] = *(const short8*)(vrow + col0);
        }
        #pragma unroll
        for (int u = 0; u < 4; ++u) {
            short8 wf;
            wf[0]=f2bf(w0[u][0]); wf[1]=f2bf(w0[u][1]); wf[2]=f2bf(w0[u][2]); wf[3]=f2bf(w0[u][3]);
            wf[4]=f2bf(w1[u][0]); wf[5]=f2bf(w1[u][1]); wf[6]=f2bf(w1[u][2]); wf[7]=f2bf(w1[u][3]);
            oacc = __builtin_amdgcn_mfma_f32_16x16x32_bf16(wf, vf[u], oacc, 0, 0, 0);
        }
    }
    // C/D: oacc[i] = PV[t = g*4+i][hd-local = r]; hd = wave*16 + r
    for (int i = 0; i < 4; ++i)
        AO[((size_t)(b * TT + t0 + g*4 + i)) * DQq + h * HDim + wave * 16 + r] = oacc[i];
}

extern "C" void kernel_launch(void* const* d_in, const int* in_sizes, int n_in,
                              void* d_out, int out_size, void* d_ws, size_t ws_size,
                              hipStream_t stream)
{
    const float* query = (const float*)d_in[0];
    const float* key   = (const float*)d_in[1];
    const float* value = (const float*)d_in[2];
    const int*   kpm   = (const int*)d_in[3];
    const float* amask = (const float*)d_in[4];
    const float* Wq = (const float*)d_in[5];
    const float* bq = (const float*)d_in[6];
    const float* Wk = (const float*)d_in[7];
    const float* bk = (const float*)d_in[8];
    const float* Wv = (const float*)d_in[9];
    const float* bv = (const float*)d_in[10];
    const float* Wo = (const float*)d_in[11];
    const float* bo = (const float*)d_in[12];

    char* ws = (char*)d_ws;
    short* WqT = (short*)ws;  ws += (size_t)512 * 512 * 2;
    short* WkT = (short*)ws;  ws += (size_t)512 * 1024 * 2;
    short* WvT = (short*)ws;  ws += (size_t)512 * 1024 * 2;
    short* WoT = (short*)ws;  ws += (size_t)512 * 512 * 2;
    short* Qh  = (short*)ws;  ws += (size_t)BB * NH * TT * HDim * 2;
    short* Kh  = (short*)ws;  ws += (size_t)BB * NH * SSZ * HDim * 2;
    short* Vth = (short*)ws;  ws += (size_t)BB * NH * HDim * SSZ * 2;
    float* AOf = (float*)ws;  ws += (size_t)BB * TT * DQq * 4;

    float* out0  = (float*)d_out;
    float* attnW = out0 + (size_t)BB * TT * DQq;

    wt_kernel<<<(512*512)/256, 256, 0, stream>>>(Wq, WqT, 512);
    wt_kernel<<<(1024*512)/256, 256, 0, stream>>>(Wk, WkT, 1024);
    wt_kernel<<<(1024*512)/256, 256, 0, stream>>>(Wv, WvT, 1024);
    wt_kernel<<<(512*512)/256, 256, 0, stream>>>(Wo, WoT, 512);

    dim3 gp(8192 / 64, 512 / 64);
    gemm_proj<0, false><<<gp, 256, 0, stream>>>(query, WqT, bq, Qh, 512);
    gemm_proj<0, false><<<gp, 256, 0, stream>>>(key,   WkT, bk, Kh, 1024);
    gemm_proj<1, false><<<gp, 256, 0, stream>>>(value, WvT, bv, Vth, 1024);

    dim3 ga(TT / 16, BB * NH);
    attn_w<<<ga, 256, 0, stream>>>(Qh, Kh, kpm, amask, attnW);
    pv_mfma<<<ga, 256, 0, stream>>>(attnW, Vth, AOf);

    gemm_proj<2, false><<<gp, 256, 0, stream>>>(AOf, WoT, bo, out0, 512);
}

// Round 10
// 575.852 us; speedup vs baseline: 1.3158x; 1.3158x over previous
//
#include <hip/hip_runtime.h>
#include <hip/hip_bf16.h>

#define BB 4
#define TT 2048
#define SSZ 2048
#define DQq 512
#define NH 8
#define HDim 64

typedef __attribute__((ext_vector_type(8))) short short8;
typedef __attribute__((ext_vector_type(4))) float f32x4;

__device__ __forceinline__ short f2bf(float f) {
    union { float f; unsigned u; } v; v.f = f;
    unsigned r = v.u + 0x7fffu + ((v.u >> 16) & 1u);
    return (short)(r >> 16);
}

// ---------------- weight transpose + bf16 convert: W[Kd][512] -> Wt[512][Kd]
// (verified round 5)
__global__ void wt_kernel(const float* __restrict__ W, short* __restrict__ Wt, int Kd) {
    int tid = blockIdx.x * 256 + threadIdx.x;
    int n = tid / Kd, k = tid - n * Kd;
    Wt[tid] = f2bf(W[(size_t)k * DQq + n]);
}

// ---------------- projection GEMM (verified round 5, unchanged)
template<int MODE, bool IN_BF16>
__global__ __launch_bounds__(256) void gemm_proj(
    const void* __restrict__ Xv, const short* __restrict__ Wt,
    const float* __restrict__ bias, void* __restrict__ Out, int Kd)
{
    __shared__ short As[64 * 40];
    __shared__ short Bs[64 * 40];
    int tid = threadIdx.x;
    int wave = tid >> 6, lane = tid & 63;
    int g = lane >> 4, r = lane & 15;
    int wm = wave >> 1, wn = wave & 1;
    int m0 = blockIdx.x * 64, n0 = blockIdx.y * 64;

    const float* Xf = (const float*)Xv;
    const short* Xb = (const short*)Xv;

    f32x4 acc[2][2];
    for (int a = 0; a < 2; ++a) for (int b2 = 0; b2 < 2; ++b2) acc[a][b2] = (f32x4){0.f,0.f,0.f,0.f};

    int lrow = tid >> 2, lk = (tid & 3) * 8;

    for (int k0 = 0; k0 < Kd; k0 += 32) {
        short8 av;
        if (IN_BF16) {
            av = *(const short8*)(Xb + (size_t)(m0 + lrow) * Kd + k0 + lk);
        } else {
            const f32x4* p = (const f32x4*)(Xf + (size_t)(m0 + lrow) * Kd + k0 + lk);
            f32x4 x0 = p[0], x1 = p[1];
            av[0]=f2bf(x0[0]); av[1]=f2bf(x0[1]); av[2]=f2bf(x0[2]); av[3]=f2bf(x0[3]);
            av[4]=f2bf(x1[0]); av[5]=f2bf(x1[1]); av[6]=f2bf(x1[2]); av[7]=f2bf(x1[3]);
        }
        *(short8*)(As + lrow * 40 + lk) = av;
        short8 bv = *(const short8*)(Wt + (size_t)(n0 + lrow) * Kd + k0 + lk);
        *(short8*)(Bs + lrow * 40 + lk) = bv;
        __syncthreads();
        short8 af[2], bf[2];
        for (int mi = 0; mi < 2; ++mi)
            af[mi] = *(short8*)(As + (wm*32 + mi*16 + r) * 40 + g*8);
        for (int ni = 0; ni < 2; ++ni)
            bf[ni] = *(short8*)(Bs + (wn*32 + ni*16 + r) * 40 + g*8);
        for (int mi = 0; mi < 2; ++mi)
            for (int ni = 0; ni < 2; ++ni)
                acc[mi][ni] = __builtin_amdgcn_mfma_f32_16x16x32_bf16(af[mi], bf[ni], acc[mi][ni], 0, 0, 0);
        __syncthreads();
    }

    for (int mi = 0; mi < 2; ++mi)
      for (int ni = 0; ni < 2; ++ni)
        for (int i = 0; i < 4; ++i) {
            int m = m0 + wm*32 + mi*16 + g*4 + i;
            int n = n0 + wn*32 + ni*16 + r;
            float v = acc[mi][ni][i] + bias[n];
            if (MODE == 0) {
                int b = m >> 11, t = m & 2047, h = n >> 6, hd = n & 63;
                ((short*)Out)[((((size_t)b*NH + h)*TT + t) << 6) + hd] = f2bf(v);
            } else if (MODE == 1) {
                int b = m >> 11, t = m & 2047, h = n >> 6, hd = n & 63;
                ((short*)Out)[(((size_t)b*NH + h)*HDim + hd)*SSZ + t] = f2bf(v);
            } else {
                ((float*)Out)[(size_t)m * DQq + n] = v;
            }
        }
}

// ---------------- attention weights only (verified round 8, unchanged)
__global__ __launch_bounds__(256) void attn_w(
    const short* __restrict__ Q, const short* __restrict__ K,
    const int* __restrict__ kpm, const float* __restrict__ amask,
    float* __restrict__ attnW)
{
    __shared__ float s_wm[4][16];
    __shared__ float s_wl[4][16];
    __shared__ float s_m[16];
    __shared__ float s_li[16];

    int tid = threadIdx.x;
    int wave = tid >> 6, lane = tid & 63;
    int g = lane >> 4, r = lane & 15;
    int t0 = blockIdx.x * 16;
    int bh = blockIdx.y;
    int b = bh >> 3;

    const short* Qp = Q + ((size_t)bh * TT + t0) * HDim;
    const short* Kp = K + (size_t)bh * SSZ * HDim;

    short8 qf0 = *(const short8*)(Qp + r * HDim + g * 8);
    short8 qf1 = *(const short8*)(Qp + r * HDim + 32 + g * 8);

    int ws0 = wave * 512;
    float mrun[4], lrun[4];
    for (int i = 0; i < 4; ++i) { mrun[i] = -1e30f; lrun[i] = 0.f; }

    // ---- phase 1: online stats (verified)
    for (int c = 0; c < 32; ++c) {
        int s_idx = ws0 + c * 16 + r;
        short8 kf0 = *(const short8*)(Kp + (size_t)s_idx * HDim + g * 8);
        short8 kf1 = *(const short8*)(Kp + (size_t)s_idx * HDim + 32 + g * 8);
        f32x4 sc = (f32x4){0.f,0.f,0.f,0.f};
        sc = __builtin_amdgcn_mfma_f32_16x16x32_bf16(qf0, kf0, sc, 0, 0, 0);
        sc = __builtin_amdgcn_mfma_f32_16x16x32_bf16(qf1, kf1, sc, 0, 0, 0);
        int ok = kpm[b * SSZ + s_idx];
        for (int i = 0; i < 4; ++i) {
            float v = sc[i] * 0.125f + amask[(size_t)(t0 + g*4 + i) * SSZ + s_idx];
            if (!ok) v = -1e30f;
            float mn = fmaxf(mrun[i], v);
            lrun[i] = lrun[i] * __expf(mrun[i] - mn) + __expf(v - mn);
            mrun[i] = mn;
        }
    }
    for (int i = 0; i < 4; ++i) {
        for (int off = 1; off < 16; off <<= 1) {
            float mo = __shfl_xor(mrun[i], off);
            float lo = __shfl_xor(lrun[i], off);
            float mn = fmaxf(mrun[i], mo);
            lrun[i] = lrun[i] * __expf(mrun[i] - mn) + lo * __expf(mo - mn);
            mrun[i] = mn;
        }
    }
    if (r == 0)
        for (int i = 0; i < 4; ++i) {
            s_wm[wave][g * 4 + i] = mrun[i];
            s_wl[wave][g * 4 + i] = lrun[i];
        }
    __syncthreads();
    if (tid < 16) {
        float m = -1e30f;
        for (int w = 0; w < 4; ++w) m = fmaxf(m, s_wm[w][tid]);
        float l = 0.f;
        for (int w = 0; w < 4; ++w) l += s_wl[w][tid] * __expf(s_wm[w][tid] - m);
        s_m[tid] = m;
        s_li[tid] = 1.0f / l;
    }
    __syncthreads();

    // ---- phase 2: recompute, normalize, write weights (verified pattern)
    float mr[4], lr[4];
    for (int i = 0; i < 4; ++i) { mr[i] = s_m[g*4 + i]; lr[i] = s_li[g*4 + i]; }

    for (int c2 = 0; c2 < 32; ++c2) {
        int s_idx = ws0 + c2 * 16 + r;
        short8 kf0 = *(const short8*)(Kp + (size_t)s_idx * HDim + g * 8);
        short8 kf1 = *(const short8*)(Kp + (size_t)s_idx * HDim + 32 + g * 8);
        f32x4 sc = (f32x4){0.f,0.f,0.f,0.f};
        sc = __builtin_amdgcn_mfma_f32_16x16x32_bf16(qf0, kf0, sc, 0, 0, 0);
        sc = __builtin_amdgcn_mfma_f32_16x16x32_bf16(qf1, kf1, sc, 0, 0, 0);
        int ok = kpm[b * SSZ + s_idx];
        for (int i = 0; i < 4; ++i) {
            float v = sc[i] * 0.125f + amask[(size_t)(t0 + g*4 + i) * SSZ + s_idx];
            if (!ok) v = -1e30f;
            float w = __expf(v - mr[i]) * lr[i];
            attnW[((size_t)bh * TT + t0 + g*4 + i) * SSZ + s_idx] = w;
        }
    }
}

// ---------------- PV via MFMA (round-8-verified fragment math; CHANGED:
// cooperative double-buffered LDS staging of the w-tile — removes the 4x
// redundant per-wave global gather and hides HBM latency under compute.
// Accumulation order identical -> identical numerics)
#define PVPAD 260   // row pitch (f32): +4 pad -> within-phase 2-way LDS reads (free)

__global__ __launch_bounds__(256) void pv_mfma(
    const float* __restrict__ attnW, const short* __restrict__ Vt,
    float* __restrict__ AO)
{
    __shared__ float wS[2][16][PVPAD];

    int tid = threadIdx.x;
    int wave = tid >> 6, lane = tid & 63;
    int g = lane >> 4, r = lane & 15;
    int t0 = blockIdx.x * 16;
    int bh = blockIdx.y;
    int b = bh >> 3, h = bh & 7;

    const float* wbase = attnW + ((size_t)bh * TT + t0) * SSZ;
    const short* vrow = Vt + ((size_t)bh * HDim + wave * 16 + r) * SSZ;

    int scol = (tid & 63) * 4;   // staging: each lane covers 4 f32 of one row

    // prefetch chunk 0 into regs, write buf 0
    f32x4 stg[4];
    #pragma unroll
    for (int p = 0; p < 4; ++p)
        stg[p] = *(const f32x4*)(wbase + (size_t)(wave + p * 4) * SSZ + scol);
    #pragma unroll
    for (int p = 0; p < 4; ++p)
        *(f32x4*)&wS[0][wave + p * 4][scol] = stg[p];

    f32x4 oacc = (f32x4){0.f, 0.f, 0.f, 0.f};

    for (int ch = 0; ch < 8; ++ch) {
        int buf = ch & 1;
        // issue next chunk's global loads early (latency hides under compute)
        if (ch < 7) {
            #pragma unroll
            for (int p = 0; p < 4; ++p)
                stg[p] = *(const f32x4*)(wbase + (size_t)(wave + p * 4) * SSZ
                                         + (ch + 1) * 256 + scol);
        }
        // current chunk's V fragments (global, L2-resident)
        short8 vf[8];
        #pragma unroll
        for (int s = 0; s < 8; ++s)
            vf[s] = *(const short8*)(vrow + ch * 256 + s * 32 + g * 8);

        __syncthreads();   // buf(ch) fully written; prior reads of buf^1 done

        #pragma unroll
        for (int s = 0; s < 8; ++s) {
            const float* wp = &wS[buf][r][s * 32 + g * 8];
            f32x4 w0 = *(const f32x4*)wp;
            f32x4 w1 = *(const f32x4*)(wp + 4);
            short8 wf;
            wf[0]=f2bf(w0[0]); wf[1]=f2bf(w0[1]); wf[2]=f2bf(w0[2]); wf[3]=f2bf(w0[3]);
            wf[4]=f2bf(w1[0]); wf[5]=f2bf(w1[1]); wf[6]=f2bf(w1[2]); wf[7]=f2bf(w1[3]);
            oacc = __builtin_amdgcn_mfma_f32_16x16x32_bf16(wf, vf[s], oacc, 0, 0, 0);
        }

        if (ch < 7) {
            #pragma unroll
            for (int p = 0; p < 4; ++p)
                *(f32x4*)&wS[buf ^ 1][wave + p * 4][scol] = stg[p];
        }
    }

    // C/D: oacc[i] = PV[t = g*4+i][hd-local = r]; hd = wave*16 + r  (verified r8)
    for (int i = 0; i < 4; ++i)
        AO[((size_t)(b * TT + t0 + g*4 + i)) * DQq + h * HDim + wave * 16 + r] = oacc[i];
}

extern "C" void kernel_launch(void* const* d_in, const int* in_sizes, int n_in,
                              void* d_out, int out_size, void* d_ws, size_t ws_size,
                              hipStream_t stream)
{
    const float* query = (const float*)d_in[0];
    const float* key   = (const float*)d_in[1];
    const float* value = (const float*)d_in[2];
    const int*   kpm   = (const int*)d_in[3];
    const float* amask = (const float*)d_in[4];
    const float* Wq = (const float*)d_in[5];
    const float* bq = (const float*)d_in[6];
    const float* Wk = (const float*)d_in[7];
    const float* bk = (const float*)d_in[8];
    const float* Wv = (const float*)d_in[9];
    const float* bv = (const float*)d_in[10];
    const float* Wo = (const float*)d_in[11];
    const float* bo = (const float*)d_in[12];

    char* ws = (char*)d_ws;
    short* WqT = (short*)ws;  ws += (size_t)512 * 512 * 2;
    short* WkT = (short*)ws;  ws += (size_t)512 * 1024 * 2;
    short* WvT = (short*)ws;  ws += (size_t)512 * 1024 * 2;
    short* WoT = (short*)ws;  ws += (size_t)512 * 512 * 2;
    short* Qh  = (short*)ws;  ws += (size_t)BB * NH * TT * HDim * 2;
    short* Kh  = (short*)ws;  ws += (size_t)BB * NH * SSZ * HDim * 2;
    short* Vth = (short*)ws;  ws += (size_t)BB * NH * HDim * SSZ * 2;
    float* AOf = (float*)ws;  ws += (size_t)BB * TT * DQq * 4;

    float* out0  = (float*)d_out;
    float* attnW = out0 + (size_t)BB * TT * DQq;

    wt_kernel<<<(512*512)/256, 256, 0, stream>>>(Wq, WqT, 512);
    wt_kernel<<<(1024*512)/256, 256, 0, stream>>>(Wk, WkT, 1024);
    wt_kernel<<<(1024*512)/256, 256, 0, stream>>>(Wv, WvT, 1024);
    wt_kernel<<<(512*512)/256, 256, 0, stream>>>(Wo, WoT, 512);

    dim3 gp(8192 / 64, 512 / 64);
    gemm_proj<0, false><<<gp, 256, 0, stream>>>(query, WqT, bq, Qh, 512);
    gemm_proj<0, false><<<gp, 256, 0, stream>>>(key,   WkT, bk, Kh, 1024);
    gemm_proj<1, false><<<gp, 256, 0, stream>>>(value, WvT, bv, Vth, 1024);

    dim3 ga(TT / 16, BB * NH);
    attn_w<<<ga, 256, 0, stream>>>(Qh, Kh, kpm, amask, attnW);
    pv_mfma<<<ga, 256, 0, stream>>>(attnW, Vth, AOf);

    gemm_proj<2, false><<<gp, 256, 0, stream>>>(AOf, WoT, bo, out0, 512);
}

// Round 11
// 554.255 us; speedup vs baseline: 1.3671x; 1.0390x over previous
//
#include <hip/hip_runtime.h>
#include <hip/hip_bf16.h>

#define BB 4
#define TT 2048
#define SSZ 2048
#define DQq 512
#define NH 8
#define HDim 64

typedef __attribute__((ext_vector_type(8))) short short8;
typedef __attribute__((ext_vector_type(4))) float f32x4;

__device__ __forceinline__ short f2bf(float f) {
    union { float f; unsigned u; } v; v.f = f;
    unsigned r = v.u + 0x7fffu + ((v.u >> 16) & 1u);
    return (short)(r >> 16);
}

// ---------------- weight transpose + bf16 convert: W[Kd][512] -> Wt[512][Kd]
// (verified round 5)
__global__ void wt_kernel(const float* __restrict__ W, short* __restrict__ Wt, int Kd) {
    int tid = blockIdx.x * 256 + threadIdx.x;
    int n = tid / Kd, k = tid - n * Kd;
    Wt[tid] = f2bf(W[(size_t)k * DQq + n]);
}

// ---------------- projection GEMM (verified round 5, unchanged)
template<int MODE, bool IN_BF16>
__global__ __launch_bounds__(256) void gemm_proj(
    const void* __restrict__ Xv, const short* __restrict__ Wt,
    const float* __restrict__ bias, void* __restrict__ Out, int Kd)
{
    __shared__ short As[64 * 40];
    __shared__ short Bs[64 * 40];
    int tid = threadIdx.x;
    int wave = tid >> 6, lane = tid & 63;
    int g = lane >> 4, r = lane & 15;
    int wm = wave >> 1, wn = wave & 1;
    int m0 = blockIdx.x * 64, n0 = blockIdx.y * 64;

    const float* Xf = (const float*)Xv;
    const short* Xb = (const short*)Xv;

    f32x4 acc[2][2];
    for (int a = 0; a < 2; ++a) for (int b2 = 0; b2 < 2; ++b2) acc[a][b2] = (f32x4){0.f,0.f,0.f,0.f};

    int lrow = tid >> 2, lk = (tid & 3) * 8;

    for (int k0 = 0; k0 < Kd; k0 += 32) {
        short8 av;
        if (IN_BF16) {
            av = *(const short8*)(Xb + (size_t)(m0 + lrow) * Kd + k0 + lk);
        } else {
            const f32x4* p = (const f32x4*)(Xf + (size_t)(m0 + lrow) * Kd + k0 + lk);
            f32x4 x0 = p[0], x1 = p[1];
            av[0]=f2bf(x0[0]); av[1]=f2bf(x0[1]); av[2]=f2bf(x0[2]); av[3]=f2bf(x0[3]);
            av[4]=f2bf(x1[0]); av[5]=f2bf(x1[1]); av[6]=f2bf(x1[2]); av[7]=f2bf(x1[3]);
        }
        *(short8*)(As + lrow * 40 + lk) = av;
        short8 bv = *(const short8*)(Wt + (size_t)(n0 + lrow) * Kd + k0 + lk);
        *(short8*)(Bs + lrow * 40 + lk) = bv;
        __syncthreads();
        short8 af[2], bf[2];
        for (int mi = 0; mi < 2; ++mi)
            af[mi] = *(short8*)(As + (wm*32 + mi*16 + r) * 40 + g*8);
        for (int ni = 0; ni < 2; ++ni)
            bf[ni] = *(short8*)(Bs + (wn*32 + ni*16 + r) * 40 + g*8);
        for (int mi = 0; mi < 2; ++mi)
            for (int ni = 0; ni < 2; ++ni)
                acc[mi][ni] = __builtin_amdgcn_mfma_f32_16x16x32_bf16(af[mi], bf[ni], acc[mi][ni], 0, 0, 0);
        __syncthreads();
    }

    for (int mi = 0; mi < 2; ++mi)
      for (int ni = 0; ni < 2; ++ni)
        for (int i = 0; i < 4; ++i) {
            int m = m0 + wm*32 + mi*16 + g*4 + i;
            int n = n0 + wn*32 + ni*16 + r;
            float v = acc[mi][ni][i] + bias[n];
            if (MODE == 0) {
                int b = m >> 11, t = m & 2047, h = n >> 6, hd = n & 63;
                ((short*)Out)[((((size_t)b*NH + h)*TT + t) << 6) + hd] = f2bf(v);
            } else if (MODE == 1) {
                int b = m >> 11, t = m & 2047, h = n >> 6, hd = n & 63;
                ((short*)Out)[(((size_t)b*NH + h)*HDim + hd)*SSZ + t] = f2bf(v);
            } else {
                ((float*)Out)[(size_t)m * DQq + n] = v;
            }
        }
}

// ---------------- FUSED attention: stats + weights (verified r8) + PV
// (verified r10 LDS-staged body) in one kernel. The block re-reads its own
// just-written 128 KB w-tile -> L2/L3-hot, removing the 512 MB HBM re-read.
#define PVPAD 260   // row pitch (f32): +4 pad

__global__ __launch_bounds__(256) void attn_pv(
    const short* __restrict__ Q, const short* __restrict__ K,
    const short* __restrict__ Vt,
    const int* __restrict__ kpm, const float* __restrict__ amask,
    float* attnW, float* __restrict__ AO)
{
    __shared__ float s_wm[4][16];
    __shared__ float s_wl[4][16];
    __shared__ float s_m[16];
    __shared__ float s_li[16];
    __shared__ float wS[2][16][PVPAD];

    int tid = threadIdx.x;
    int wave = tid >> 6, lane = tid & 63;
    int g = lane >> 4, r = lane & 15;
    int t0 = blockIdx.x * 16;
    int bh = blockIdx.y;
    int b = bh >> 3, h = bh & 7;

    const short* Qp = Q + ((size_t)bh * TT + t0) * HDim;
    const short* Kp = K + (size_t)bh * SSZ * HDim;

    short8 qf0 = *(const short8*)(Qp + r * HDim + g * 8);
    short8 qf1 = *(const short8*)(Qp + r * HDim + 32 + g * 8);

    int ws0 = wave * 512;
    float mrun[4], lrun[4];
    for (int i = 0; i < 4; ++i) { mrun[i] = -1e30f; lrun[i] = 0.f; }

    // ---- phase 1: online stats (verified r8, byte-identical)
    for (int c = 0; c < 32; ++c) {
        int s_idx = ws0 + c * 16 + r;
        short8 kf0 = *(const short8*)(Kp + (size_t)s_idx * HDim + g * 8);
        short8 kf1 = *(const short8*)(Kp + (size_t)s_idx * HDim + 32 + g * 8);
        f32x4 sc = (f32x4){0.f,0.f,0.f,0.f};
        sc = __builtin_amdgcn_mfma_f32_16x16x32_bf16(qf0, kf0, sc, 0, 0, 0);
        sc = __builtin_amdgcn_mfma_f32_16x16x32_bf16(qf1, kf1, sc, 0, 0, 0);
        int ok = kpm[b * SSZ + s_idx];
        for (int i = 0; i < 4; ++i) {
            float v = sc[i] * 0.125f + amask[(size_t)(t0 + g*4 + i) * SSZ + s_idx];
            if (!ok) v = -1e30f;
            float mn = fmaxf(mrun[i], v);
            lrun[i] = lrun[i] * __expf(mrun[i] - mn) + __expf(v - mn);
            mrun[i] = mn;
        }
    }
    for (int i = 0; i < 4; ++i) {
        for (int off = 1; off < 16; off <<= 1) {
            float mo = __shfl_xor(mrun[i], off);
            float lo = __shfl_xor(lrun[i], off);
            float mn = fmaxf(mrun[i], mo);
            lrun[i] = lrun[i] * __expf(mrun[i] - mn) + lo * __expf(mo - mn);
            mrun[i] = mn;
        }
    }
    if (r == 0)
        for (int i = 0; i < 4; ++i) {
            s_wm[wave][g * 4 + i] = mrun[i];
            s_wl[wave][g * 4 + i] = lrun[i];
        }
    __syncthreads();
    if (tid < 16) {
        float m = -1e30f;
        for (int w = 0; w < 4; ++w) m = fmaxf(m, s_wm[w][tid]);
        float l = 0.f;
        for (int w = 0; w < 4; ++w) l += s_wl[w][tid] * __expf(s_wm[w][tid] - m);
        s_m[tid] = m;
        s_li[tid] = 1.0f / l;
    }
    __syncthreads();

    // ---- phase 2: recompute, normalize, write weights (verified r8)
    float mr[4], lr[4];
    for (int i = 0; i < 4; ++i) { mr[i] = s_m[g*4 + i]; lr[i] = s_li[g*4 + i]; }

    for (int c2 = 0; c2 < 32; ++c2) {
        int s_idx = ws0 + c2 * 16 + r;
        short8 kf0 = *(const short8*)(Kp + (size_t)s_idx * HDim + g * 8);
        short8 kf1 = *(const short8*)(Kp + (size_t)s_idx * HDim + 32 + g * 8);
        f32x4 sc = (f32x4){0.f,0.f,0.f,0.f};
        sc = __builtin_amdgcn_mfma_f32_16x16x32_bf16(qf0, kf0, sc, 0, 0, 0);
        sc = __builtin_amdgcn_mfma_f32_16x16x32_bf16(qf1, kf1, sc, 0, 0, 0);
        int ok = kpm[b * SSZ + s_idx];
        for (int i = 0; i < 4; ++i) {
            float v = sc[i] * 0.125f + amask[(size_t)(t0 + g*4 + i) * SSZ + s_idx];
            if (!ok) v = -1e30f;
            float w = __expf(v - mr[i]) * lr[i];
            attnW[((size_t)bh * TT + t0 + g*4 + i) * SSZ + s_idx] = w;
        }
    }

    // ---- make this block's attnW writes visible to its own reads
    __threadfence_block();
    __syncthreads();

    // ---- phase 3: PV (verified r10 LDS-staged body, byte-identical indices)
    const float* wbase = attnW + ((size_t)bh * TT + t0) * SSZ;
    const short* vrow = Vt + ((size_t)bh * HDim + wave * 16 + r) * SSZ;

    int scol = (tid & 63) * 4;

    f32x4 stg[4];
    #pragma unroll
    for (int p = 0; p < 4; ++p)
        stg[p] = *(const f32x4*)(wbase + (size_t)(wave + p * 4) * SSZ + scol);
    #pragma unroll
    for (int p = 0; p < 4; ++p)
        *(f32x4*)&wS[0][wave + p * 4][scol] = stg[p];

    f32x4 oacc = (f32x4){0.f, 0.f, 0.f, 0.f};

    for (int ch = 0; ch < 8; ++ch) {
        int buf = ch & 1;
        if (ch < 7) {
            #pragma unroll
            for (int p = 0; p < 4; ++p)
                stg[p] = *(const f32x4*)(wbase + (size_t)(wave + p * 4) * SSZ
                                         + (ch + 1) * 256 + scol);
        }
        short8 vf[8];
        #pragma unroll
        for (int s = 0; s < 8; ++s)
            vf[s] = *(const short8*)(vrow + ch * 256 + s * 32 + g * 8);

        __syncthreads();

        #pragma unroll
        for (int s = 0; s < 8; ++s) {
            const float* wp = &wS[buf][r][s * 32 + g * 8];
            f32x4 w0 = *(const f32x4*)wp;
            f32x4 w1 = *(const f32x4*)(wp + 4);
            short8 wf;
            wf[0]=f2bf(w0[0]); wf[1]=f2bf(w0[1]); wf[2]=f2bf(w0[2]); wf[3]=f2bf(w0[3]);
            wf[4]=f2bf(w1[0]); wf[5]=f2bf(w1[1]); wf[6]=f2bf(w1[2]); wf[7]=f2bf(w1[3]);
            oacc = __builtin_amdgcn_mfma_f32_16x16x32_bf16(wf, vf[s], oacc, 0, 0, 0);
        }

        if (ch < 7) {
            #pragma unroll
            for (int p = 0; p < 4; ++p)
                *(f32x4*)&wS[buf ^ 1][wave + p * 4][scol] = stg[p];
        }
    }

    // C/D: oacc[i] = PV[t = g*4+i][hd-local = r]; hd = wave*16 + r (verified r8)
    for (int i = 0; i < 4; ++i)
        AO[((size_t)(b * TT + t0 + g*4 + i)) * DQq + h * HDim + wave * 16 + r] = oacc[i];
}

extern "C" void kernel_launch(void* const* d_in, const int* in_sizes, int n_in,
                              void* d_out, int out_size, void* d_ws, size_t ws_size,
                              hipStream_t stream)
{
    const float* query = (const float*)d_in[0];
    const float* key   = (const float*)d_in[1];
    const float* value = (const float*)d_in[2];
    const int*   kpm   = (const int*)d_in[3];
    const float* amask = (const float*)d_in[4];
    const float* Wq = (const float*)d_in[5];
    const float* bq = (const float*)d_in[6];
    const float* Wk = (const float*)d_in[7];
    const float* bk = (const float*)d_in[8];
    const float* Wv = (const float*)d_in[9];
    const float* bv = (const float*)d_in[10];
    const float* Wo = (const float*)d_in[11];
    const float* bo = (const float*)d_in[12];

    char* ws = (char*)d_ws;
    short* WqT = (short*)ws;  ws += (size_t)512 * 512 * 2;
    short* WkT = (short*)ws;  ws += (size_t)512 * 1024 * 2;
    short* WvT = (short*)ws;  ws += (size_t)512 * 1024 * 2;
    short* WoT = (short*)ws;  ws += (size_t)512 * 512 * 2;
    short* Qh  = (short*)ws;  ws += (size_t)BB * NH * TT * HDim * 2;
    short* Kh  = (short*)ws;  ws += (size_t)BB * NH * SSZ * HDim * 2;
    short* Vth = (short*)ws;  ws += (size_t)BB * NH * HDim * SSZ * 2;
    float* AOf = (float*)ws;  ws += (size_t)BB * TT * DQq * 4;

    float* out0  = (float*)d_out;
    float* attnW = out0 + (size_t)BB * TT * DQq;

    wt_kernel<<<(512*512)/256, 256, 0, stream>>>(Wq, WqT, 512);
    wt_kernel<<<(1024*512)/256, 256, 0, stream>>>(Wk, WkT, 1024);
    wt_kernel<<<(1024*512)/256, 256, 0, stream>>>(Wv, WvT, 1024);
    wt_kernel<<<(512*512)/256, 256, 0, stream>>>(Wo, WoT, 512);

    dim3 gp(8192 / 64, 512 / 64);
    gemm_proj<0, false><<<gp, 256, 0, stream>>>(query, WqT, bq, Qh, 512);
    gemm_proj<0, false><<<gp, 256, 0, stream>>>(key,   WkT, bk, Kh, 1024);
    gemm_proj<1, false><<<gp, 256, 0, stream>>>(value, WvT, bv, Vth, 1024);

    dim3 ga(TT / 16, BB * NH);
    attn_pv<<<ga, 256, 0, stream>>>(Qh, Kh, Vth, kpm, amask, attnW, AOf);

    gemm_proj<2, false><<<gp, 256, 0, stream>>>(AOf, WoT, bo, out0, 512);
}